// Round 1
// baseline (650.525 us; speedup 1.0000x reference)
//
#include <hip/hip_runtime.h>
#include <stdint.h>

#define NQ 10000
#define NC 2048
#define NW 157           // ceil(10000/64)
#define IOU_TH 0.5f

// -------- ws layout (bytes) --------
// scores : [0,       40000)
// rank   : [40000,   80000)
// boxes4 : [80000,  240000)   10000*4 f32 (xyxy, clipped+scaled)
// sx1    : [240000, 280000)   sorted SoA
// sy1    : [280000, 320000)
// sx2    : [320000, 360000)
// sy2    : [360000, 400000)
// sarea  : [400000, 440000)
// order  : [440000, 480000)   sorted index -> original index
// mask   : [480000, 480000+10000*157*8 = 13,040,000)

__global__ __launch_bounds__(256) void k_scores(const float* __restrict__ logits,
        float* __restrict__ out_scores, float* __restrict__ out_labels,
        float* __restrict__ ws_scores) {
    int wave = threadIdx.x >> 6;
    int lane = threadIdx.x & 63;
    int q = blockIdx.x * 4 + wave;
    if (q >= NQ) return;
    const float* row = logits + (size_t)q * NC;
    float4 v[8];
    float m = -3.4e38f;
    int am = 0;
    #pragma unroll
    for (int k = 0; k < 8; k++) {
        int idx = k * 256 + lane * 4;
        v[k] = *(const float4*)(row + idx);
        // strict > keeps first occurrence within this lane's ascending indices
        if (v[k].x > m) { m = v[k].x; am = idx; }
        if (v[k].y > m) { m = v[k].y; am = idx + 1; }
        if (v[k].z > m) { m = v[k].z; am = idx + 2; }
        if (v[k].w > m) { m = v[k].w; am = idx + 3; }
    }
    #pragma unroll
    for (int off = 32; off >= 1; off >>= 1) {
        float om = __shfl_xor(m, off);
        int   oa = __shfl_xor(am, off);
        if (om > m || (om == m && oa < am)) { m = om; am = oa; }
    }
    float s = 0.f;
    #pragma unroll
    for (int k = 0; k < 8; k++) {
        s += expf(v[k].x - m);
        s += expf(v[k].y - m);
        s += expf(v[k].z - m);
        s += expf(v[k].w - m);
    }
    #pragma unroll
    for (int off = 32; off >= 1; off >>= 1) s += __shfl_xor(s, off);
    if (lane == 0) {
        float sc = 1.0f / s;           // max prob = exp(0)/sum = 1/sum
        out_scores[q] = sc;
        out_labels[q] = (float)am;
        ws_scores[q]  = sc;
    }
}

__global__ __launch_bounds__(256) void k_cls(const float* __restrict__ cls,
                                             float* __restrict__ out) {
    float m = -3.4e38f; int am = 0x7fffffff;
    for (int idx = threadIdx.x; idx < NC; idx += 256) {
        float x = cls[idx];
        if (x > m) { m = x; am = idx; }    // per-thread indices ascending
    }
    int lane = threadIdx.x & 63, wave = threadIdx.x >> 6;
    #pragma unroll
    for (int off = 32; off >= 1; off >>= 1) {
        float om = __shfl_xor(m, off); int oa = __shfl_xor(am, off);
        if (om > m || (om == m && oa < am)) { m = om; am = oa; }
    }
    __shared__ float sm[4]; __shared__ int sa[4];
    if (lane == 0) { sm[wave] = m; sa[wave] = am; }
    __syncthreads();
    if (threadIdx.x == 0) {
        for (int w = 1; w < 4; w++)
            if (sm[w] > m || (sm[w] == m && sa[w] < am)) { m = sm[w]; am = sa[w]; }
        out[0] = (float)am;
    }
}

__global__ __launch_bounds__(256) void k_boxes(const float* __restrict__ pb,
        const int* __restrict__ ts, float* __restrict__ out_boxes,
        float* __restrict__ boxes4, int* __restrict__ rank) {
    #pragma clang fp contract(off)
    int i = blockIdx.x * 256 + threadIdx.x;
    if (i >= NQ) return;
    rank[i] = 0;
    // target_sizes may be int64 (low/high word pairs) or int32; values in [480,1333)
    int a0 = ts[0], a1 = ts[1];
    int ih, iw;
    if (a1 == 0) { ih = a0; iw = ts[2]; } else { ih = a0; iw = a1; }
    float sh = (float)ih, sw = (float)iw;
    float4 b = *(const float4*)(pb + i * 4);
    float x1 = b.x - 0.5f * b.z;
    float y1 = b.y - 0.5f * b.w;
    float x2 = b.x + 0.5f * b.z;
    float y2 = b.y + 0.5f * b.w;
    x1 = fminf(fmaxf(x1, 0.f), 1.f) * sw;
    y1 = fminf(fmaxf(y1, 0.f), 1.f) * sh;
    x2 = fminf(fmaxf(x2, 0.f), 1.f) * sw;
    y2 = fminf(fmaxf(y2, 0.f), 1.f) * sh;
    float4 o = make_float4(x1, y1, x2, y2);
    *(float4*)(out_boxes + i * 4) = o;
    *(float4*)(boxes4 + i * 4) = o;
}

// rank[i] = #{j: s_j > s_i} + #{j: s_j == s_i && j < i}  == position in argsort(-s) (stable)
__global__ __launch_bounds__(256) void k_count(const float* __restrict__ scores,
                                               int* __restrict__ rank) {
    __shared__ float sc[2000];
    int jbase = blockIdx.y * 2000;
    int jn = min(2000, NQ - jbase);
    for (int t = threadIdx.x; t < jn; t += 256) sc[t] = scores[jbase + t];
    __syncthreads();
    int i = blockIdx.x * 256 + threadIdx.x;
    if (i >= NQ) return;
    float si = scores[i];
    int cnt = 0;
    for (int jj = 0; jj < jn; jj++) {
        float sj = sc[jj];
        int j = jbase + jj;
        cnt += (sj > si) || (sj == si && j < i);
    }
    if (cnt) atomicAdd(&rank[i], cnt);
}

__global__ __launch_bounds__(256) void k_scatter(const float* __restrict__ boxes4,
        const int* __restrict__ rank, int* __restrict__ order,
        float* __restrict__ sx1, float* __restrict__ sy1,
        float* __restrict__ sx2, float* __restrict__ sy2,
        float* __restrict__ sarea) {
    #pragma clang fp contract(off)
    int i = blockIdx.x * 256 + threadIdx.x;
    if (i >= NQ) return;
    int r = rank[i];
    order[r] = i;
    float4 b = *(const float4*)(boxes4 + i * 4);
    sx1[r] = b.x; sy1[r] = b.y; sx2[r] = b.z; sy2[r] = b.w;
    sarea[r] = fmaxf(b.z - b.x, 0.f) * fmaxf(b.w - b.y, 0.f);
}

// mask[i][cb] bit jj = (j>i) && IoU(i, j)>0.5, j = cb*64+jj (sorted order)
__global__ __launch_bounds__(64) void k_mask(const float* __restrict__ sx1,
        const float* __restrict__ sy1, const float* __restrict__ sx2,
        const float* __restrict__ sy2, const float* __restrict__ sarea,
        unsigned long long* __restrict__ mask) {
    #pragma clang fp contract(off)
    int rb = blockIdx.x, cb = blockIdx.y;
    if (cb < rb) return;
    int t = threadIdx.x;
    __shared__ float cx1[64], cy1[64], cx2[64], cy2[64], ca[64];
    int j0 = cb * 64 + t;
    if (j0 < NQ) { cx1[t]=sx1[j0]; cy1[t]=sy1[j0]; cx2[t]=sx2[j0]; cy2[t]=sy2[j0]; ca[t]=sarea[j0]; }
    __syncthreads();
    int i = rb * 64 + t;
    if (i >= NQ) return;
    float xi1 = sx1[i], yi1 = sy1[i], xi2 = sx2[i], yi2 = sy2[i], ai = sarea[i];
    int ncol = min(64, NQ - cb * 64);
    unsigned long long word = 0;
    for (int jj = 0; jj < ncol; jj++) {
        int j = cb * 64 + jj;
        float lx = fmaxf(xi1, cx1[jj]);
        float ly = fmaxf(yi1, cy1[jj]);
        float rx = fminf(xi2, cx2[jj]);
        float ry = fminf(yi2, cy2[jj]);
        float w = fmaxf(rx - lx, 0.f);
        float h = fmaxf(ry - ly, 0.f);
        float inter = w * h;
        float denom = (ai + ca[jj]) - inter;   // ref op order: (areas[i]+areas)-inter
        float iou = inter / denom;
        bool sup = (iou > IOU_TH) && (j > i);
        word |= ((unsigned long long)(sup ? 1u : 0u)) << jj;
    }
    mask[(size_t)i * NW + cb] = word;
}

// Single-wave sequential greedy reduce — pipelined so NO memory round trip sits
// on the per-chunk critical path:
//   * crit words (c+1, c+2) of ALL 64 candidate rows of a chunk are prefetched
//     2 chunks ahead; after resolve, kept rows' contribution is gathered with
//     v_readlane (scalar), not loads.
//   * bulk suffix words (> c+2) of kept rows go into ping-pong register
//     buffers (PA/PB) issued at chunk c, consumed at chunk c+2 (~2 chunk-times
//     of latency slack).
//   * diag word + order prefetched 2 chunks ahead (dg/dgN stages).
// Word-w coverage for a row kept in chunk c': w=c' via diag (resolve), w=c'+1
// via A (crit.x), w=c'+2 via B (crit.y, applied 2 chunks later), w>=c'+3 via
// bulk (consumed at c'+2 <= w). OR is idempotent so overlaps are harmless.
__global__ __launch_bounds__(64) void k_scan(const unsigned long long* __restrict__ mask,
        const int* __restrict__ order, float* __restrict__ out_keep) {
    const int lane = threadIdx.x & 63;
    uint64_t r0 = 0, r1 = 0, r2 = 0;     // removed words: lane, lane+64, lane+128
    const int w0 = lane, w1 = lane + 64, w2 = lane + 128;
    const bool w2v = (w2 < NW);

    // ping-pong bulk buffers + leftover temp (all static-indexed -> registers)
    uint64_t PA[8][3], PB[8][3], T[8][3];
    #pragma unroll
    for (int t = 0; t < 8; t++) {
        #pragma unroll
        for (int k = 0; k < 3; k++) { PA[t][k] = 0; PB[t][k] = 0; }
    }

    auto rl32 = [](uint32_t v, int b) -> uint32_t {
        return (uint32_t)__builtin_amdgcn_readlane((int)v, b);
    };

    // current-chunk state (chunk c) and next-chunk stage (chunk c+1)
    uint32_t dg_lo, dg_hi;  uint64_t cx, cy;  int ord;
    uint32_t dgN_lo, dgN_hi; uint64_t cxN, cyN; int ordN;
    {
        const unsigned long long* rp0 = mask + (size_t)lane * NW;
        uint64_t d0 = rp0[0];
        cx = rp0[1]; cy = rp0[2];
        ord = order[lane];
        const unsigned long long* rp1 = mask + (size_t)(64 + lane) * NW;
        uint64_t d1 = rp1[1];
        cxN = rp1[2]; cyN = rp1[3];
        ordN = order[64 + lane];
        dg_lo = (uint32_t)d0; dg_hi = (uint32_t)(d0 >> 32);
        dgN_lo = (uint32_t)d1; dgN_hi = (uint32_t)(d1 >> 32);
    }

    // scalar pending crit contributions:
    //   A_prev = word-(c) contribution from chunk c-1's kept rows
    //   B_prev2 = word-(c) contribution from chunk c-2's kept rows
    uint64_t A_prev = 0, B_prev = 0, B_prev2 = 0;

    auto issue8 = [&](uint64_t (&buf)[8][3], uint64_t& kmr, int c) {
        #pragma unroll
        for (int t = 0; t < 8; t++) {
            uint64_t x0 = 0, x1 = 0, x2 = 0;
            if (kmr) {
                int b = (int)__builtin_ctzll(kmr); kmr &= kmr - 1;
                const unsigned long long* rp = mask + (size_t)(c * 64 + b) * NW;
                if (w0 > c + 2)        x0 = rp[w0];
                if (w1 > c + 2)        x1 = rp[w1];
                if (w2v && w2 > c + 2) x2 = rp[w2];
            }
            buf[t][0] = x0; buf[t][1] = x1; buf[t][2] = x2;
        }
    };
    auto consume8 = [&](uint64_t (&buf)[8][3]) {
        uint64_t a0 = 0, a1 = 0, a2 = 0;
        #pragma unroll
        for (int t = 0; t < 8; t++) { a0 |= buf[t][0]; a1 |= buf[t][1]; a2 |= buf[t][2]; }
        r0 |= a0; r1 |= a1; r2 |= a2;
    };

    auto chunk = [&](int c, uint64_t (&P)[8][3]) {
        // ---- issue prefetch for chunk c+2 (independent of resolve) ----
        uint32_t dgT_lo = 0, dgT_hi = 0; uint64_t cxT = 0, cyT = 0; int ordT = 0;
        if (c + 2 < NW) {
            int i2 = (c + 2) * 64 + lane;
            if (i2 < NQ) {
                const unsigned long long* rp = mask + (size_t)i2 * NW;
                uint64_t d = rp[c + 2];
                dgT_lo = (uint32_t)d; dgT_hi = (uint32_t)(d >> 32);
                ordT = order[i2];
                if (c + 3 < NW) cxT = rp[c + 3];
                if (c + 4 < NW) cyT = rp[c + 4];
            }
        }

        // ---- consume bulk_{c-2} (issued ~2 chunk-times ago: latency hidden) ----
        consume8(P);

        // ---- removed word for chunk c ----
        int cl = c & 63;
        uint32_t rlo, rhi;
        if (c < 64)       { rlo = rl32((uint32_t)r0, cl); rhi = rl32((uint32_t)(r0 >> 32), cl); }
        else if (c < 128) { rlo = rl32((uint32_t)r1, cl); rhi = rl32((uint32_t)(r1 >> 32), cl); }
        else              { rlo = rl32((uint32_t)r2, cl); rhi = rl32((uint32_t)(r2 >> 32), cl); }
        uint64_t cur = (((uint64_t)rhi << 32) | rlo) | A_prev | B_prev2;
        int nvalid = min(64, NQ - c * 64);
        if (nvalid < 64) cur |= (~0ull) << nvalid;   // invalid tail = suppressed

        // ---- scalar greedy resolve over alive bits ----
        uint64_t alive = ~cur;
        uint64_t kept = 0;
        while (alive) {
            int b = (int)__builtin_ctzll(alive);
            uint64_t d = ((uint64_t)rl32(dg_hi, b) << 32) | rl32(dg_lo, b);
            kept  |= 1ull << b;
            cur   |= d;
            alive &= ~(d | (1ull << b));
        }

        // ---- write keep for this chunk ----
        int i = c * 64 + lane;
        if (i < NQ) out_keep[ord] = ((cur >> lane) & 1ull) ? 0.f : 1.f;

        // ---- crit contributions (words c+1, c+2) via readlane: no loads ----
        uint64_t Ac = 0, Bc = 0, km = kept;
        while (km) {
            int b = (int)__builtin_ctzll(km); km &= km - 1;
            Ac |= ((uint64_t)rl32((uint32_t)(cx >> 32), b) << 32) | rl32((uint32_t)cx, b);
            Bc |= ((uint64_t)rl32((uint32_t)(cy >> 32), b) << 32) | rl32((uint32_t)cy, b);
        }

        // ---- issue bulk_c (words > c+2) into P; leftovers exposed (rare) ----
        uint64_t kmr = kept;
        issue8(P, kmr, c);
        while (kmr) { issue8(T, kmr, c); consume8(T); }

        // ---- rotate pipeline state ----
        B_prev2 = B_prev; B_prev = Bc; A_prev = Ac;
        dg_lo = dgN_lo; dg_hi = dgN_hi; cx = cxN; cy = cyN; ord = ordN;
        dgN_lo = dgT_lo; dgN_hi = dgT_hi; cxN = cxT; cyN = cyT; ordN = ordT;
    };

    // unrolled by 2 so the ping-pong buffer binding is static (registers, not scratch)
    for (int c = 0; c < NW; c += 2) {
        chunk(c, PA);
        if (c + 1 < NW) chunk(c + 1, PB);
    }
}

extern "C" void kernel_launch(void* const* d_in, const int* in_sizes, int n_in,
                              void* d_out, int out_size, void* d_ws, size_t ws_size,
                              hipStream_t stream) {
    const float* pred_logits = (const float*)d_in[0];
    const float* pred_boxes  = (const float*)d_in[1];
    const float* cls_logits  = (const float*)d_in[2];
    const int*   tsizes      = (const int*)d_in[3];

    float* out = (float*)d_out;
    float* out_scores = out;
    float* out_labels = out + 10000;
    float* out_boxes  = out + 20000;
    float* out_keep   = out + 60000;
    float* out_cls    = out + 70000;

    char* ws = (char*)d_ws;
    float* ws_scores = (float*)(ws + 0);
    int*   rank      = (int*)  (ws + 40000);
    float* boxes4    = (float*)(ws + 80000);
    float* sx1       = (float*)(ws + 240000);
    float* sy1       = (float*)(ws + 280000);
    float* sx2       = (float*)(ws + 320000);
    float* sy2       = (float*)(ws + 360000);
    float* sarea     = (float*)(ws + 400000);
    int*   order     = (int*)  (ws + 440000);
    unsigned long long* mask = (unsigned long long*)(ws + 480000);

    k_scores<<<2500, 256, 0, stream>>>(pred_logits, out_scores, out_labels, ws_scores);
    k_cls<<<1, 256, 0, stream>>>(cls_logits, out_cls);
    k_boxes<<<40, 256, 0, stream>>>(pred_boxes, tsizes, out_boxes, boxes4, rank);
    k_count<<<dim3(40, 5), 256, 0, stream>>>(ws_scores, rank);
    k_scatter<<<40, 256, 0, stream>>>(boxes4, rank, order, sx1, sy1, sx2, sy2, sarea);
    k_mask<<<dim3(157, 157), 64, 0, stream>>>(sx1, sy1, sx2, sy2, sarea, mask);
    k_scan<<<1, 64, 0, stream>>>(mask, order, out_keep);
}